// Round 21
// baseline (429.142 us; speedup 1.0000x reference)
//
#include <hip/hip_runtime.h>
#include <hip/hip_bf16.h>
#include <stdint.h>

#define HW 192
#define PLANE (HW * HW)
#define PH 194
#define PPG (PH * PH)      // 37636 granules per padded 8-ch plane

typedef __attribute__((ext_vector_type(8))) short frag8;
typedef __attribute__((ext_vector_type(16))) float f32x16;
typedef unsigned short ushort_t;

__device__ __forceinline__ ushort_t b16(float v) {
    __hip_bfloat16 b = __float2bfloat16(v);
    return __builtin_bit_cast(ushort_t, b);
}

// async 16B global->LDS copy: per-lane global src, wave-uniform LDS base (+lane*16)
__device__ __forceinline__ void gld_lds16(const ushort_t* g, ushort_t* s) {
    __builtin_amdgcn_global_load_lds(
        (const __attribute__((address_space(1))) uint32_t*)(const void*)g,
        (__attribute__((address_space(3))) uint32_t*)(void*)s, 16, 0, 0);
}

template<int N> __device__ __forceinline__ void vmcnt_wait() {
    static_assert(N == 0 || N == 6, "unsupported vmcnt");
    if constexpr (N == 0) asm volatile("s_waitcnt vmcnt(0)" ::: "memory");
    else if constexpr (N == 6) asm volatile("s_waitcnt vmcnt(6)" ::: "memory");
}

// W[O][C_IN][3][3] f32 -> wt [NOB][NCHUNK][10][OTC][8] bf16 (tap slot 9 and o>=C_OUT zero)
__global__ __launch_bounds__(256) void wtrans_kernel(
    const float* __restrict__ w, ushort_t* __restrict__ wt,
    int C_IN, int C_OUT, int NCHUNK, int OTC, int total)
{
    for (int idx = blockIdx.x * 256 + threadIdx.x; idx < total; idx += gridDim.x * 256) {
        int ic = idx & 7;
        int g = idx >> 3;
        int o = g % OTC; g /= OTC;
        int t = g % 10;  g /= 10;
        int c8 = g % NCHUNK;
        int ob = g / NCHUNK;
        int og = ob * OTC + o;
        float v = 0.f;
        if (t < 9 && og < C_OUT)
            v = w[((size_t)og * C_IN + c8 * 8 + ic) * 9 + t];
        wt[idx] = b16(v);
    }
}

// src [nb*64][H][W] f32 -> per-batch padded bf16 planes [8][PH][PH][8] at b*bstr
__global__ __launch_bounds__(256) void packfx_kernel(
    const float* __restrict__ src, ushort_t* __restrict__ d,
    int nb, size_t bstr)
{
    int n = nb * 64 * PLANE;
    for (int idx = blockIdx.x * 256 + threadIdx.x; idx < n; idx += gridDim.x * 256) {
        int c = idx / PLANE;
        int p = idx - c * PLANE;
        int b = c >> 6, cc = c & 63;
        int y = p / HW, x = p - y * HW;
        size_t di = (size_t)b * bstr + ((size_t)(cc >> 3) * PPG + (size_t)(y + 1) * PH + (x + 1)) * 8 + (cc & 7);
        d[di] = b16(src[idx]);
    }
}

// zero the 1-px borders of nchunks padded planes
__global__ __launch_bounds__(256) void zborder_kernel(
    ushort_t* __restrict__ ph, int nchunks)
{
    int total = nchunks * 772;
    for (int i = blockIdx.x * 256 + threadIdx.x; i < total; i += gridDim.x * 256) {
        int chunk = i / 772, b = i - chunk * 772;
        int y, x;
        if (b < 194)      { y = 0;   x = b; }
        else if (b < 388) { y = 193; x = b - 194; }
        else { int r = b - 388; y = 1 + (r >> 1); x = (r & 1) ? 193 : 0; }
        size_t g = ((size_t)chunk * PPG + (size_t)y * PH + x) * 8;
        *(uint4*)&ph[g] = make_uint4(0, 0, 0, 0);
    }
}

// 3x3 SAME conv, single-pass bf16 MFMA (32x32x16), T4 counted-vmcnt pipeline:
// raw s_barrier + s_waitcnt vmcnt(6) — prefetch loads stay in flight across the
// barrier. Every wave issues EXACTLY 6 loads per chunk (slots padded; pad lanes
// clamp the GLOBAL address, landing in LDS pad never read) so vmcnt is uniform.
// inp: [NCHUNK][PH][PH][8] per batch; wt: [NOB][NCHUNK][10][OTC][8]. blockIdx.z=batch.
// Block: 256 thr (4 waves), (4*MF rows)x32 tile, MF one-row m-frags/wave
// (one-row frags -> conflict-free A-reads, r13/r14-verified).
// Variants: MF=4/OTC=64 (conv1/conv2, NF=2); MF=2/OTC=96 (conv3, NF=3 -> 38.4
// FLOP per LDS byte vs 25.6 at the old OTC=32/NF=1 blocking).
// K-step = 16 = 2 tap-slots x 8 ic; 10 tap-slots (slot 9 zero) -> 5 k-steps/chunk.
// A row / B col = lane&31; k-octet = lane>>5 (tap); same contiguous-8 k-labeling both
// sides -> HW k-permutation cancels. C/D: col=lane&31, m=(reg&3)+8(reg>>2)+4(lane>>5).
// NOTE: no min-waves hint (rounds 5/8: hint below acc footprint -> scratch spill).
template<int NCHUNK, int OTC, int MF, bool LAST>
__global__ __launch_bounds__(256) void conv_mfma(
    const ushort_t* __restrict__ inp, const ushort_t* __restrict__ wt,
    const float* __restrict__ bias, int c_out,
    ushort_t* __restrict__ outp, float* __restrict__ outf,
    size_t in_bstr, size_t out_bstr, size_t outf_bstr)
{
    constexpr int NF = OTC / 32;
    constexpr int TSY = 4 * MF;
    constexpr int HGR2 = (TSY + 2) * 34;      // halo granules (612 or 340)
    constexpr int HITER = (MF == 4) ? 3 : 2;  // halo slots per wave
    constexpr int HPADG = HITER * 4 * 64;     // LDS granules per halo buffer
    constexpr int WGR = 10 * OTC;             // weight granules per chunk slab
    constexpr int WITER = (OTC == 64) ? 3 : 4;    // weight slots per wave (96->4)
    constexpr int WPADG = WITER * 4 * 64;     // LDS granules per weight buffer
    static_assert(HITER + WITER == 6, "uniform vmcnt immediate");
    __shared__ ushort_t s_x[2 * HPADG * 8];
    __shared__ ushort_t s_w[2 * WPADG * 8];

    const int tid = threadIdx.x;
    const int wv = tid >> 6;          // 0..3
    const int lane = tid & 63;
    const int ln31 = lane & 31;       // A row (pixel col) / B col (o) / D col
    const int lhalf = lane >> 5;      // k-octet -> tap select within k-step
    const int tx0 = (blockIdx.x % 6) * 32;
    const int ty0 = (blockIdx.x / 6) * TSY;
    const int ob = blockIdx.y;
    const int bz = blockIdx.z;

    const ushort_t* bin = inp + (size_t)bz * in_bstr;

    // m-frag = one row of 32 px; wave wv owns rows wv*MF .. wv*MF+MF-1
    int pixbase[MF];
    #pragma unroll
    for (int mf = 0; mf < MF; ++mf)
        pixbase[mf] = ((wv * MF + mf) * 34 + ln31) * 8;

    // per-lane tap offset into halo + weight slot, per k-step
    int hof[5], wslot[5];
    #pragma unroll
    for (int ks = 0; ks < 5; ++ks) {
        int t = ks * 2 + lhalf;
        wslot[ks] = t;
        int te = t > 8 ? 8 : t;   // pad slot 9 reads tap8's (valid) address; B there is zero
        int dy = te >= 6 ? 2 : (te >= 3 ? 1 : 0);
        int dx = te - dy * 3;
        hof[ks] = (dy * 34 + dx) * 8;
    }

    f32x16 acc[MF][NF];
    #pragma unroll
    for (int mf = 0; mf < MF; ++mf)
        #pragma unroll
        for (int nf = 0; nf < NF; ++nf) {
            int o = ob * OTC + nf * 32 + ln31;
            float bv = (o < c_out) ? bias[o] : 0.f;
            #pragma unroll
            for (int r = 0; r < 16; ++r) acc[mf][nf][r] = bv;
        }

    const ushort_t* wbase = wt + (size_t)ob * NCHUNK * WGR * 8;

    // exactly HITER+WITER (=6) gld_lds per wave per call (clamped, no divergence)
    auto stage = [&](int buf, int c8) {
        const ushort_t* ih = bin + (size_t)c8 * PPG * 8;
        ushort_t* dx = s_x + buf * (HPADG * 8);
        #pragma unroll
        for (int i = 0; i < HITER; ++i) {
            int j = wv * HITER + i;
            int hg = j * 64 + lane;
            int hgc = hg < HGR2 ? hg : HGR2 - 1;   // clamp: pad lanes re-load last granule
            int r = hgc / 34, c = hgc - r * 34;
            size_t sg = ((size_t)(ty0 + r) * PH + (tx0 + c)) * 8;
            gld_lds16(&ih[sg], &dx[j * 64 * 8]);
        }
        const ushort_t* wch = wbase + (size_t)c8 * WGR * 8;
        ushort_t* dw = s_w + buf * (WPADG * 8);
        #pragma unroll
        for (int i = 0; i < WITER; ++i) {
            int j = wv * WITER + i;
            int wg = j * 64 + lane;
            int wgc = wg < WGR ? wg : WGR - 1;
            gld_lds16(&wch[(size_t)wgc * 8], &dw[j * 64 * 8]);
        }
    };

    // prologue: chunks 0 and 1 in flight; drain (simple/safe, once per kernel)
    stage(0, 0);
    if (NCHUNK > 1) stage(1, 1);
    vmcnt_wait<0>();
    __builtin_amdgcn_s_barrier();
    __builtin_amdgcn_sched_barrier(0);

    for (int c8 = 0; c8 < NCHUNK; ++c8) {
        const int cur = c8 & 1;
        const ushort_t* xh = s_x + cur * (HPADG * 8);
        const ushort_t* wh = s_w + cur * (WPADG * 8);
        #pragma unroll
        for (int ks = 0; ks < 5; ++ks) {
            frag8 bh[NF];
            #pragma unroll
            for (int nf = 0; nf < NF; ++nf)
                bh[nf] = *(const frag8*)&wh[(wslot[ks] * OTC + nf * 32 + ln31) * 8];
            #pragma unroll
            for (int mf = 0; mf < MF; ++mf) {
                frag8 ah = *(const frag8*)&xh[pixbase[mf] + hof[ks]];
                #pragma unroll
                for (int nf = 0; nf < NF; ++nf)
                    acc[mf][nf] = __builtin_amdgcn_mfma_f32_32x32x16_bf16(ah, bh[nf], acc[mf][nf], 0, 0, 0);
            }
        }
        if (c8 + 1 == NCHUNK) break;
        __builtin_amdgcn_sched_barrier(0);
        __builtin_amdgcn_s_barrier();          // A: all waves done reading buf[cur]
        if (c8 + 2 < NCHUNK) {
            stage(cur, c8 + 2);                // overwrite buf[cur] with chunk c8+2
            vmcnt_wait<6>();                   // wait for chunk c8+1's loads only
        } else {
            vmcnt_wait<0>();                   // tail: nothing new issued
        }
        __builtin_amdgcn_s_barrier();          // B: chunk c8+1's loads have landed
        __builtin_amdgcn_sched_barrier(0);
    }

    // ---- epilogue: reg j=4i+r: px col m = 8i + 4*lhalf + r; row = wv*MF+mf ----
    #pragma unroll
    for (int mf = 0; mf < MF; ++mf) {
        int gy = ty0 + wv * MF + mf;
        #pragma unroll
        for (int nf = 0; nf < NF; ++nf) {
            int o = ob * OTC + nf * 32 + ln31;
            if (o < c_out) {
                #pragma unroll
                for (int i = 0; i < 4; ++i) {
                    int px = tx0 + i * 8 + lhalf * 4;
                    if constexpr (LAST) {
                        float* boutf = outf + (size_t)bz * outf_bstr;
                        float4 v = make_float4(acc[mf][nf][4 * i + 0], acc[mf][nf][4 * i + 1],
                                               acc[mf][nf][4 * i + 2], acc[mf][nf][4 * i + 3]);
                        *(float4*)&boutf[(size_t)o * PLANE + gy * HW + px] = v;
                    } else {
                        ushort_t* bout = outp + (size_t)bz * out_bstr;
                        size_t g0 = ((size_t)(o >> 3) * PPG + (size_t)(gy + 1) * PH + (px + 1)) * 8 + (o & 7);
                        #pragma unroll
                        for (int r = 0; r < 4; ++r)
                            bout[g0 + (size_t)r * 8] = b16(acc[mf][nf][4 * i + r]);
                    }
                }
            }
        }
    }
}

// nb batches. out[b,c,y,x] = sum_p ks_b[p*3+c, y, x] * xpad[b, c, y+p/5-2, x+p%5-2]
__global__ __launch_bounds__(256) void apply_kernel(
    const float* __restrict__ x, const float* __restrict__ ks,
    float* __restrict__ out, int nb, size_t ks_bstr)
{
    int tid = blockIdx.x * 256 + threadIdx.x;
    int total = nb * PLANE;
    if (tid >= total) return;
    int b = tid / PLANE;
    int pix = tid - b * PLANE;
    int y = pix / HW;
    int xc = pix - y * HW;

    const float* xb  = x  + (size_t)b * 3 * PLANE;
    const float* ksb = ks + (size_t)b * ks_bstr;
    float* ob        = out + (size_t)b * 3 * PLANE;

    float acc[3] = {0.f, 0.f, 0.f};
    #pragma unroll
    for (int p = 0; p < 25; ++p) {
        const int di = p / 5, dj = p % 5;
        int yy = y + di - 2, xx = xc + dj - 2;
        bool inb = (yy >= 0 && yy < HW && xx >= 0 && xx < HW);
        #pragma unroll
        for (int c = 0; c < 3; ++c) {
            float kv = ksb[((size_t)(p * 3 + c) * HW + y) * HW + xc];
            float xv = inb ? xb[((size_t)c * HW + yy) * HW + xx] : 0.f;
            acc[c] = fmaf(kv, xv, acc[c]);
        }
    }
    #pragma unroll
    for (int c = 0; c < 3; ++c)
        ob[((size_t)c * HW + y) * HW + xc] = acc[c];
}

extern "C" void kernel_launch(void* const* d_in, const int* in_sizes, int n_in,
                              void* d_out, int out_size, void* d_ws, size_t ws_size,
                              hipStream_t stream) {
    const float* feature_x = (const float*)d_in[0];
    const float* x  = (const float*)d_in[1];
    const float* W1 = (const float*)d_in[2];
    const float* b1 = (const float*)d_in[3];
    const float* W2 = (const float*)d_in[4];
    const float* b2 = (const float*)d_in[5];
    const float* W3 = (const float*)d_in[6];
    const float* b3 = (const float*)d_in[7];
    float* out = (float*)d_out;

    const size_t PLN32 = (size_t)32 * PPG * 8;   // 9,634,816 ush (single bf16 plane/batch)
    const size_t PLN8  = (size_t)8 * PPG * 8;    // 2,408,704 ush
    const size_t W1SZ = 163840, W2SZ = 655360, W3SZ = 245760;
    const size_t WTOT = W1SZ + W2SZ + W3SZ;      // 1,064,960 ush
    // NB=4: y1[4] + y2[4] + weights = 156,286,976 B <= 158,416,896 B proven (r16).
    const size_t FULL4 = (8 * PLN32 + WTOT) * 2;
    const int NB = (ws_size >= FULL4) ? 4 : 2;   // NB=2 path: 79.2 MB

    ushort_t* y1 = (ushort_t*)d_ws;              // [NB] planes, stride PLN32
    ushort_t* y2 = y1 + (size_t)NB * PLN32;
    ushort_t* wb = y2 + (size_t)NB * PLN32;
    ushort_t* w1 = wb;
    ushort_t* w2 = w1 + W1SZ;
    ushort_t* w3 = w2 + W2SZ;
    ushort_t* fx  = y2;                          // fx aliases y2 region, stride PLN8
    float*    ksf = (float*)y1;                  // ks aliases y1 region, stride PLN32/2 f32

    const size_t KS_BSTR = PLN32 / 2;            // f32 units

    dim3 blk(256);
    wtrans_kernel<<<256, blk, 0, stream>>>(W1, w1, 64, 256, 8, 64, (int)W1SZ);
    wtrans_kernel<<<256, blk, 0, stream>>>(W2, w2, 256, 256, 32, 64, (int)W2SZ);
    wtrans_kernel<<<256, blk, 0, stream>>>(W3, w3, 256, 75, 32, 96, (int)W3SZ);

    // conv1/conv2: MF=4 tile 16x32 -> 72 spatial; conv3: MF=2/OTC=96 tile 8x32 -> 144 spatial
    dim3 g12(72, 4, NB), g3(144, 1, NB);
    dim3 ga((NB * PLANE + 255) / 256);
    for (int bp = 0; bp < 4 / NB; ++bp) {
        const float* fxsrc = feature_x + (size_t)bp * NB * 64 * PLANE;
        const float* x_b   = x   + (size_t)bp * NB * 3 * PLANE;
        float* out_b       = out + (size_t)bp * NB * 3 * PLANE;
        // Re-zero borders EVERY group: prev group's ks (aliasing y1) clobbered y1
        // borders with f32 bit patterns (bf16-NaN hazard, r15 lesson). zborder(y2)
        // also zeroes fx borders (fx planes = leading chunks of y2 region, same geometry).
        zborder_kernel<<<97, blk, 0, stream>>>(y1, NB * 32);
        zborder_kernel<<<97, blk, 0, stream>>>(y2, NB * 32);
        packfx_kernel<<<1024, blk, 0, stream>>>(fxsrc, fx, NB, PLN8);
        conv_mfma< 8, 64, 4, false><<<g12, blk, 0, stream>>>(
            fx, w1, b1, 256, y1, nullptr, PLN8, PLN32, 0);
        conv_mfma<32, 64, 4, false><<<g12, blk, 0, stream>>>(
            y1, w2, b2, 256, y2, nullptr, PLN32, PLN32, 0);
        conv_mfma<32, 96, 2, true ><<<g3, blk, 0, stream>>>(
            y2, w3, b3, 75, nullptr, ksf, PLN32, 0, KS_BSTR);
        apply_kernel<<<ga, blk, 0, stream>>>(x_b, ksf, out_b, NB, KS_BSTR);
    }
}

// Round 22
// 396.522 us; speedup vs baseline: 1.0823x; 1.0823x over previous
//
#include <hip/hip_runtime.h>
#include <hip/hip_bf16.h>
#include <stdint.h>

#define HW 192
#define PLANE (HW * HW)
#define PH 194
#define PPG (PH * PH)      // 37636 granules per padded 8-ch plane

typedef __attribute__((ext_vector_type(8))) short frag8;
typedef __attribute__((ext_vector_type(16))) float f32x16;
typedef unsigned short ushort_t;

__device__ __forceinline__ ushort_t b16(float v) {
    __hip_bfloat16 b = __float2bfloat16(v);
    return __builtin_bit_cast(ushort_t, b);
}
__device__ __forceinline__ float b16f(ushort_t u) {
    return __bfloat162float(__builtin_bit_cast(__hip_bfloat16, u));
}

// async 16B global->LDS copy: per-lane global src, wave-uniform LDS base (+lane*16)
__device__ __forceinline__ void gld_lds16(const ushort_t* g, ushort_t* s) {
    __builtin_amdgcn_global_load_lds(
        (const __attribute__((address_space(1))) uint32_t*)(const void*)g,
        (__attribute__((address_space(3))) uint32_t*)(void*)s, 16, 0, 0);
}

template<int N> __device__ __forceinline__ void vmcnt_wait() {
    static_assert(N == 0 || N == 6, "unsupported vmcnt");
    if constexpr (N == 0) asm volatile("s_waitcnt vmcnt(0)" ::: "memory");
    else if constexpr (N == 6) asm volatile("s_waitcnt vmcnt(6)" ::: "memory");
}

// W[O][C_IN][3][3] f32 -> wt [NOB][NCHUNK][10][OTC][8] bf16 (tap slot 9 and o>=C_OUT zero)
__global__ __launch_bounds__(256) void wtrans_kernel(
    const float* __restrict__ w, ushort_t* __restrict__ wt,
    int C_IN, int C_OUT, int NCHUNK, int OTC, int total)
{
    for (int idx = blockIdx.x * 256 + threadIdx.x; idx < total; idx += gridDim.x * 256) {
        int ic = idx & 7;
        int g = idx >> 3;
        int o = g % OTC; g /= OTC;
        int t = g % 10;  g /= 10;
        int c8 = g % NCHUNK;
        int ob = g / NCHUNK;
        int og = ob * OTC + o;
        float v = 0.f;
        if (t < 9 && og < C_OUT)
            v = w[((size_t)og * C_IN + c8 * 8 + ic) * 9 + t];
        wt[idx] = b16(v);
    }
}

// src [nb*64][H][W] f32 -> per-batch padded bf16 planes [8][PH][PH][8] at b*bstr
__global__ __launch_bounds__(256) void packfx_kernel(
    const float* __restrict__ src, ushort_t* __restrict__ d,
    int nb, size_t bstr)
{
    int n = nb * 64 * PLANE;
    for (int idx = blockIdx.x * 256 + threadIdx.x; idx < n; idx += gridDim.x * 256) {
        int c = idx / PLANE;
        int p = idx - c * PLANE;
        int b = c >> 6, cc = c & 63;
        int y = p / HW, x = p - y * HW;
        size_t di = (size_t)b * bstr + ((size_t)(cc >> 3) * PPG + (size_t)(y + 1) * PH + (x + 1)) * 8 + (cc & 7);
        d[di] = b16(src[idx]);
    }
}

// zero the 1-px borders of nchunks padded planes
__global__ __launch_bounds__(256) void zborder_kernel(
    ushort_t* __restrict__ ph, int nchunks)
{
    int total = nchunks * 772;
    for (int i = blockIdx.x * 256 + threadIdx.x; i < total; i += gridDim.x * 256) {
        int chunk = i / 772, b = i - chunk * 772;
        int y, x;
        if (b < 194)      { y = 0;   x = b; }
        else if (b < 388) { y = 193; x = b - 194; }
        else { int r = b - 388; y = 1 + (r >> 1); x = (r & 1) ? 193 : 0; }
        size_t g = ((size_t)chunk * PPG + (size_t)y * PH + x) * 8;
        *(uint4*)&ph[g] = make_uint4(0, 0, 0, 0);
    }
}

// 3x3 SAME conv, single-pass bf16 MFMA (32x32x16), T4 counted-vmcnt pipeline
// (raw s_barrier + s_waitcnt vmcnt(6); prefetch loads stay in flight across the
// barrier; every wave issues EXACTLY 6 loads per chunk — slots padded, pad lanes
// clamp the GLOBAL address into LDS pad never read — so vmcnt is uniform).
// inp: [NCHUNK][PH][PH][8] per batch; wt: [NOB][NCHUNK][10][OTC][8]. blockIdx.z=batch.
// Block: 256 thr (4 waves), (4*MF rows)x32 tile, MF one-row m-frags/wave
// (one-row frags -> conflict-free A-reads, r13/r14-verified).
// Variants: MF=4/OTC=64 (conv1/conv2, NF=2); MF=2/OTC=96 (conv3, NF=3).
// LAST=true (conv3): apply is FUSED into the epilogue — the 75-channel ks tile for
// this block's 256 pixels is dumped to the (freed) staging LDS as bf16 with a
// p^((o&7)<<2) bank swizzle, then each of the 256 threads applies the 5x5x3
// per-pixel kernel for its own pixel, reading x from global. Eliminates the
// 44MB ks write + 44MB ks read + the separate apply dispatch.
// K-step = 16 = 2 tap-slots x 8 ic; 10 tap-slots (slot 9 zero) -> 5 k-steps/chunk.
// A row / B col = lane&31; k-octet = lane>>5 (tap); same contiguous-8 k-labeling both
// sides -> HW k-permutation cancels. C/D: col=lane&31, m=(reg&3)+8(reg>>2)+4(lane>>5).
// NOTE: no min-waves hint (rounds 5/8: hint below acc footprint -> scratch spill).
template<int NCHUNK, int OTC, int MF, bool LAST>
__global__ __launch_bounds__(256) void conv_mfma(
    const ushort_t* __restrict__ inp, const ushort_t* __restrict__ wt,
    const float* __restrict__ bias, int c_out,
    ushort_t* __restrict__ outp, const float* __restrict__ xin,
    float* __restrict__ outf, size_t in_bstr, size_t out_bstr)
{
    constexpr int NF = OTC / 32;
    constexpr int TSY = 4 * MF;
    constexpr int HGR2 = (TSY + 2) * 34;      // halo granules (612 or 340)
    constexpr int HITER = (MF == 4) ? 3 : 2;  // halo slots per wave
    constexpr int HPADG = HITER * 4 * 64;     // LDS granules per halo buffer
    constexpr int WGR = 10 * OTC;             // weight granules per chunk slab
    constexpr int WITER = (OTC == 64) ? 3 : 4;    // weight slots per wave (96->4)
    constexpr int WPADG = WITER * 4 * 64;     // LDS granules per weight buffer
    static_assert(HITER + WITER == 6, "uniform vmcnt immediate");
    constexpr int SMEM_USH = 2 * HPADG * 8 + 2 * WPADG * 8;   // 24576 both variants
    static_assert(!LAST || SMEM_USH >= 96 * 256, "ks tile must fit staging LDS");
    __shared__ ushort_t smem[SMEM_USH];
    ushort_t* s_x = smem;                     // 2 halo buffers
    ushort_t* s_w = smem + 2 * HPADG * 8;     // 2 weight buffers

    const int tid = threadIdx.x;
    const int wv = tid >> 6;          // 0..3
    const int lane = tid & 63;
    const int ln31 = lane & 31;       // A row (pixel col) / B col (o) / D col
    const int lhalf = lane >> 5;      // k-octet -> tap select within k-step
    const int tx0 = (blockIdx.x % 6) * 32;
    const int ty0 = (blockIdx.x / 6) * TSY;
    const int ob = blockIdx.y;
    const int bz = blockIdx.z;

    const ushort_t* bin = inp + (size_t)bz * in_bstr;

    // m-frag = one row of 32 px; wave wv owns rows wv*MF .. wv*MF+MF-1
    int pixbase[MF];
    #pragma unroll
    for (int mf = 0; mf < MF; ++mf)
        pixbase[mf] = ((wv * MF + mf) * 34 + ln31) * 8;

    // per-lane tap offset into halo + weight slot, per k-step
    int hof[5], wslot[5];
    #pragma unroll
    for (int ks = 0; ks < 5; ++ks) {
        int t = ks * 2 + lhalf;
        wslot[ks] = t;
        int te = t > 8 ? 8 : t;   // pad slot 9 reads tap8's (valid) address; B there is zero
        int dy = te >= 6 ? 2 : (te >= 3 ? 1 : 0);
        int dx = te - dy * 3;
        hof[ks] = (dy * 34 + dx) * 8;
    }

    f32x16 acc[MF][NF];
    #pragma unroll
    for (int mf = 0; mf < MF; ++mf)
        #pragma unroll
        for (int nf = 0; nf < NF; ++nf) {
            int o = ob * OTC + nf * 32 + ln31;
            float bv = (o < c_out) ? bias[o] : 0.f;
            #pragma unroll
            for (int r = 0; r < 16; ++r) acc[mf][nf][r] = bv;
        }

    const ushort_t* wbase = wt + (size_t)ob * NCHUNK * WGR * 8;

    // exactly HITER+WITER (=6) gld_lds per wave per call (clamped, no divergence)
    auto stage = [&](int buf, int c8) {
        const ushort_t* ih = bin + (size_t)c8 * PPG * 8;
        ushort_t* dx = s_x + buf * (HPADG * 8);
        #pragma unroll
        for (int i = 0; i < HITER; ++i) {
            int j = wv * HITER + i;
            int hg = j * 64 + lane;
            int hgc = hg < HGR2 ? hg : HGR2 - 1;   // clamp: pad lanes re-load last granule
            int r = hgc / 34, c = hgc - r * 34;
            size_t sg = ((size_t)(ty0 + r) * PH + (tx0 + c)) * 8;
            gld_lds16(&ih[sg], &dx[j * 64 * 8]);
        }
        const ushort_t* wch = wbase + (size_t)c8 * WGR * 8;
        ushort_t* dw = s_w + buf * (WPADG * 8);
        #pragma unroll
        for (int i = 0; i < WITER; ++i) {
            int j = wv * WITER + i;
            int wg = j * 64 + lane;
            int wgc = wg < WGR ? wg : WGR - 1;
            gld_lds16(&wch[(size_t)wgc * 8], &dw[j * 64 * 8]);
        }
    };

    // prologue: chunks 0 and 1 in flight; drain (simple/safe, once per kernel)
    stage(0, 0);
    if (NCHUNK > 1) stage(1, 1);
    vmcnt_wait<0>();
    __builtin_amdgcn_s_barrier();
    __builtin_amdgcn_sched_barrier(0);

    for (int c8 = 0; c8 < NCHUNK; ++c8) {
        const int cur = c8 & 1;
        const ushort_t* xh = s_x + cur * (HPADG * 8);
        const ushort_t* wh = s_w + cur * (WPADG * 8);
        #pragma unroll
        for (int ks = 0; ks < 5; ++ks) {
            frag8 bh[NF];
            #pragma unroll
            for (int nf = 0; nf < NF; ++nf)
                bh[nf] = *(const frag8*)&wh[(wslot[ks] * OTC + nf * 32 + ln31) * 8];
            #pragma unroll
            for (int mf = 0; mf < MF; ++mf) {
                frag8 ah = *(const frag8*)&xh[pixbase[mf] + hof[ks]];
                #pragma unroll
                for (int nf = 0; nf < NF; ++nf)
                    acc[mf][nf] = __builtin_amdgcn_mfma_f32_32x32x16_bf16(ah, bh[nf], acc[mf][nf], 0, 0, 0);
            }
        }
        if (c8 + 1 == NCHUNK) break;
        __builtin_amdgcn_sched_barrier(0);
        __builtin_amdgcn_s_barrier();          // A: all waves done reading buf[cur]
        if (c8 + 2 < NCHUNK) {
            stage(cur, c8 + 2);                // overwrite buf[cur] with chunk c8+2
            vmcnt_wait<6>();                   // wait for chunk c8+1's loads only
        } else {
            vmcnt_wait<0>();                   // tail: nothing new issued
        }
        __builtin_amdgcn_s_barrier();          // B: chunk c8+1's loads have landed
        __builtin_amdgcn_sched_barrier(0);
    }

    if constexpr (!LAST) {
        // ---- epilogue: reg j=4i+r: px col m = 8i + 4*lhalf + r; row = wv*MF+mf ----
        #pragma unroll
        for (int mf = 0; mf < MF; ++mf) {
            int gy = ty0 + wv * MF + mf;
            #pragma unroll
            for (int nf = 0; nf < NF; ++nf) {
                int o = ob * OTC + nf * 32 + ln31;
                if (o < c_out) {
                    #pragma unroll
                    for (int i = 0; i < 4; ++i) {
                        int px = tx0 + i * 8 + lhalf * 4;
                        ushort_t* bout = outp + (size_t)bz * out_bstr;
                        size_t g0 = ((size_t)(o >> 3) * PPG + (size_t)(gy + 1) * PH + (px + 1)) * 8 + (o & 7);
                        #pragma unroll
                        for (int r = 0; r < 4; ++r)
                            bout[g0 + (size_t)r * 8] = b16(acc[mf][nf][4 * i + r]);
                    }
                }
            }
        }
    } else {
        // ---- fused apply epilogue (conv3): all vm loads drained before break ----
        __builtin_amdgcn_s_barrier();          // staging LDS now free for ks tile
        // write bf16 ks tile: s_ks[o][p ^ ((o&7)<<2)], o in [0,96), p in [0,256)
        #pragma unroll
        for (int mf = 0; mf < MF; ++mf) {
            int lrow = wv * MF + mf;
            #pragma unroll
            for (int nf = 0; nf < NF; ++nf) {
                int o = nf * 32 + ln31;
                #pragma unroll
                for (int i = 0; i < 4; ++i) {
                    int pbase = lrow * 32 + i * 8 + lhalf * 4;
                    #pragma unroll
                    for (int r = 0; r < 4; ++r) {
                        int p = pbase + r;
                        smem[o * 256 + (p ^ ((o & 7) << 2))] = b16(acc[mf][nf][4 * i + r]);
                    }
                }
            }
        }
        __builtin_amdgcn_s_barrier();
        // per-thread 5x5x3 apply for its own pixel
        const int p = tid;
        const int gy = ty0 + (p >> 5);
        const int gx = tx0 + (p & 31);
        const float* xb = xin + (size_t)bz * 3 * PLANE;
        float* ob = outf + (size_t)bz * 3 * PLANE;
        float a[3] = {0.f, 0.f, 0.f};
        #pragma unroll
        for (int pt = 0; pt < 25; ++pt) {
            const int di = pt / 5, dj = pt % 5;
            int yy = gy + di - 2, xx = gx + dj - 2;
            bool inb = (yy >= 0 && yy < HW && xx >= 0 && xx < HW);
            #pragma unroll
            for (int c = 0; c < 3; ++c) {
                int k = pt * 3 + c;
                float kv = b16f(smem[k * 256 + (p ^ ((k & 7) << 2))]);
                float xv = inb ? xb[(size_t)c * PLANE + yy * HW + xx] : 0.f;
                a[c] = fmaf(kv, xv, a[c]);
            }
        }
        #pragma unroll
        for (int c = 0; c < 3; ++c)
            ob[(size_t)c * PLANE + gy * HW + gx] = a[c];
    }
}

extern "C" void kernel_launch(void* const* d_in, const int* in_sizes, int n_in,
                              void* d_out, int out_size, void* d_ws, size_t ws_size,
                              hipStream_t stream) {
    const float* feature_x = (const float*)d_in[0];
    const float* x  = (const float*)d_in[1];
    const float* W1 = (const float*)d_in[2];
    const float* b1 = (const float*)d_in[3];
    const float* W2 = (const float*)d_in[4];
    const float* b2 = (const float*)d_in[5];
    const float* W3 = (const float*)d_in[6];
    const float* b3 = (const float*)d_in[7];
    float* out = (float*)d_out;

    const size_t PLN32 = (size_t)32 * PPG * 8;   // 9,634,816 ush (single bf16 plane/batch)
    const size_t PLN8  = (size_t)8 * PPG * 8;    // 2,408,704 ush
    const size_t W1SZ = 163840, W2SZ = 655360, W3SZ = 307200;   // conv3 OTC=96
    const size_t WTOT = W1SZ + W2SZ + W3SZ;
    // NB=4: y1[4] + y2[4] + weights <= 158,416,896 B proven (r16).
    const size_t FULL4 = (8 * PLN32 + WTOT) * 2;
    const int NB = (ws_size >= FULL4) ? 4 : 2;   // NB=2 path: ~79 MB

    ushort_t* y1 = (ushort_t*)d_ws;              // [NB] planes, stride PLN32
    ushort_t* y2 = y1 + (size_t)NB * PLN32;
    ushort_t* wb = y2 + (size_t)NB * PLN32;
    ushort_t* w1 = wb;
    ushort_t* w2 = w1 + W1SZ;
    ushort_t* w3 = w2 + W2SZ;
    ushort_t* fx  = y2;                          // fx aliases y2 region, stride PLN8

    dim3 blk(256);
    wtrans_kernel<<<256, blk, 0, stream>>>(W1, w1, 64, 256, 8, 64, (int)W1SZ);
    wtrans_kernel<<<256, blk, 0, stream>>>(W2, w2, 256, 256, 32, 64, (int)W2SZ);
    wtrans_kernel<<<256, blk, 0, stream>>>(W3, w3, 256, 75, 32, 96, (int)W3SZ);

    // conv1/conv2: MF=4 tile 16x32 -> 72 spatial; conv3: MF=2/OTC=96 tile 8x32 -> 144 spatial
    dim3 g12(72, 4, NB), g3(144, 1, NB);
    for (int bp = 0; bp < 4 / NB; ++bp) {
        const float* fxsrc = feature_x + (size_t)bp * NB * 64 * PLANE;
        const float* x_b   = x   + (size_t)bp * NB * 3 * PLANE;
        float* out_b       = out + (size_t)bp * NB * 3 * PLANE;
        // Re-zero borders each call (workspace is 0xAA-poisoned before timing; the
        // epilogues only write plane interiors, so borders must be zeroed here).
        zborder_kernel<<<97, blk, 0, stream>>>(y1, NB * 32);
        zborder_kernel<<<97, blk, 0, stream>>>(y2, NB * 32);
        packfx_kernel<<<1024, blk, 0, stream>>>(fxsrc, fx, NB, PLN8);
        conv_mfma< 8, 64, 4, false><<<g12, blk, 0, stream>>>(
            fx, w1, b1, 256, y1, nullptr, nullptr, PLN8, PLN32);
        conv_mfma<32, 64, 4, false><<<g12, blk, 0, stream>>>(
            y1, w2, b2, 256, y2, nullptr, nullptr, PLN32, PLN32);
        conv_mfma<32, 96, 2, true ><<<g3, blk, 0, stream>>>(
            y2, w3, b3, 75, nullptr, x_b, out_b, PLN32, 0);
    }
}

// Round 23
// 370.910 us; speedup vs baseline: 1.1570x; 1.0691x over previous
//
#include <hip/hip_runtime.h>
#include <hip/hip_bf16.h>
#include <stdint.h>

#define HW 192
#define PLANE (HW * HW)
#define PH 194
#define PPG (PH * PH)      // 37636 granules per padded 8-ch plane

typedef __attribute__((ext_vector_type(8))) short frag8;
typedef __attribute__((ext_vector_type(16))) float f32x16;
typedef unsigned short ushort_t;

__device__ __forceinline__ ushort_t b16(float v) {
    __hip_bfloat16 b = __float2bfloat16(v);
    return __builtin_bit_cast(ushort_t, b);
}
__device__ __forceinline__ float b16f(ushort_t u) {
    return __bfloat162float(__builtin_bit_cast(__hip_bfloat16, u));
}

// async 16B global->LDS copy: per-lane global src, wave-uniform LDS base (+lane*16)
__device__ __forceinline__ void gld_lds16(const ushort_t* g, ushort_t* s) {
    __builtin_amdgcn_global_load_lds(
        (const __attribute__((address_space(1))) uint32_t*)(const void*)g,
        (__attribute__((address_space(3))) uint32_t*)(void*)s, 16, 0, 0);
}

template<int N> __device__ __forceinline__ void vmcnt_wait() {
    static_assert(N == 0 || N == 3 || N == 5, "unsupported vmcnt");
    if constexpr (N == 0) asm volatile("s_waitcnt vmcnt(0)" ::: "memory");
    else if constexpr (N == 3) asm volatile("s_waitcnt vmcnt(3)" ::: "memory");
    else if constexpr (N == 5) asm volatile("s_waitcnt vmcnt(5)" ::: "memory");
}

// W[O][C_IN][3][3] f32 -> wt [NOB][NCHUNK][9][2][OTC+4][8] bf16.
// Tap-major, 16-ic chunks: chunk cc, ic-octet h, tap t. o-pad (+4 granules) breaks
// the 1024B LDS bank alias between the two lane-half B-reads (r11 lesson).
// Pad granules and o>=C_OUT are zero.
__global__ __launch_bounds__(256) void wtrans_kernel(
    const float* __restrict__ w, ushort_t* __restrict__ wt,
    int C_IN, int C_OUT, int NCHUNK, int OTC, int total)
{
    for (int idx = blockIdx.x * 256 + threadIdx.x; idx < total; idx += gridDim.x * 256) {
        int ic = idx & 7;
        int g = idx >> 3;
        int o = g % (OTC + 4); g /= (OTC + 4);
        int h = g & 1; g >>= 1;
        int t = g % 9; g /= 9;
        int cc = g % NCHUNK;
        int ob = g / NCHUNK;
        int og = ob * OTC + o;
        float v = 0.f;
        if (o < OTC && og < C_OUT)
            v = w[((size_t)og * C_IN + cc * 16 + h * 8 + ic) * 9 + t];
        wt[idx] = b16(v);
    }
}

// src [nb*64][H][W] f32 -> per-batch padded bf16 planes [8][PH][PH][8] at b*bstr
__global__ __launch_bounds__(256) void packfx_kernel(
    const float* __restrict__ src, ushort_t* __restrict__ d,
    int nb, size_t bstr)
{
    int n = nb * 64 * PLANE;
    for (int idx = blockIdx.x * 256 + threadIdx.x; idx < n; idx += gridDim.x * 256) {
        int c = idx / PLANE;
        int p = idx - c * PLANE;
        int b = c >> 6, cc = c & 63;
        int y = p / HW, x = p - y * HW;
        size_t di = (size_t)b * bstr + ((size_t)(cc >> 3) * PPG + (size_t)(y + 1) * PH + (x + 1)) * 8 + (cc & 7);
        d[di] = b16(src[idx]);
    }
}

// zero the 1-px borders of nchunks padded planes
__global__ __launch_bounds__(256) void zborder_kernel(
    ushort_t* __restrict__ ph, int nchunks)
{
    int total = nchunks * 772;
    for (int i = blockIdx.x * 256 + threadIdx.x; i < total; i += gridDim.x * 256) {
        int chunk = i / 772, b = i - chunk * 772;
        int y, x;
        if (b < 194)      { y = 0;   x = b; }
        else if (b < 388) { y = 193; x = b - 194; }
        else { int r = b - 388; y = 1 + (r >> 1); x = (r & 1) ? 193 : 0; }
        size_t g = ((size_t)chunk * PPG + (size_t)y * PH + x) * 8;
        *(uint4*)&ph[g] = make_uint4(0, 0, 0, 0);
    }
}

// 3x3 SAME conv, single-pass bf16 MFMA (32x32x16), TAP-MAJOR K-loop:
// K-step = 16 consecutive ic (lane-half = ic-octet, same contiguous-8 labeling on
// A and B -> HW k-permutation cancels); the 9 real taps are looped explicitly ->
// zero tap-padding waste, and 16-ic chunks halve the barrier count vs r22.
// Halo double-buffered with counted vmcnt (per-wave ledger: after issuing
// w(c+1)+halo(c+2), wait vmcnt(H) -> w(c+1)+halo(c+1) landed, halo(c+2) flying).
// Weights single-buffered (L2-hot stage at barrier A, ~4% exposure).
// inp: [2*NCHUNK 8-ic planes][PH][PH][8] per batch; wt: [NOB][NCHUNK][9][2][OTC+4][8].
// Block: 256 thr (4 waves), (4*MF rows)x32 tile, MF one-row m-frags/wave.
// LAST=true (conv3): fused 5x5x3 apply epilogue via LDS ks tile (r22-verified).
// A row / B col = lane&31; C/D: col=lane&31, m=(reg&3)+8(reg>>2)+4(lane>>5).
// NOTE: no min-waves hint (rounds 5/8: hint below acc footprint -> scratch spill).
template<int NCHUNK, int OTC, int MF, bool LAST>
__global__ __launch_bounds__(256) void conv_mfma(
    const ushort_t* __restrict__ inp, const ushort_t* __restrict__ wt,
    const float* __restrict__ bias, int c_out,
    ushort_t* __restrict__ outp, const float* __restrict__ xin,
    float* __restrict__ outf, size_t in_bstr, size_t out_bstr)
{
    constexpr int NF = OTC / 32;
    constexpr int TSY = 4 * MF;
    constexpr int HGR_P = (TSY + 2) * 34;     // halo granules per 8-ic plane (612/340)
    constexpr int HGR_T = 2 * HGR_P;          // per 16-ic chunk (1224/680)
    constexpr int HSLOT = (MF == 4) ? 20 : 12;    // 64-granule slots (mult of 4)
    constexpr int HPW = HSLOT / 4;            // uniform halo loads per wave (5/3)
    constexpr int WOS = OTC + 4;              // padded o-granules per (t,h)
    constexpr int WGR = 9 * 2 * WOS;          // weight granules per chunk (1224/1800)
    constexpr int WSLOT = (WGR + 63) / 64;    // 20 / 29 (may be non-mult-of-4: ok,
                                              // vmcnt immediate only counts halo)
    constexpr int SMEM_USH = (2 * HSLOT + WSLOT) * 64 * 8;   // 30720 / 27136 ush
    static_assert(!LAST || SMEM_USH >= 96 * 256, "ks tile must fit LDS");
    __shared__ ushort_t smem[SMEM_USH];
    ushort_t* s_x = smem;                     // 2 halo buffers
    ushort_t* s_w = smem + 2 * HSLOT * 64 * 8;

    const int tid = threadIdx.x;
    const int wv = tid >> 6;          // 0..3
    const int lane = tid & 63;
    const int ln31 = lane & 31;       // A row (pixel col) / B col (o) / D col
    const int lhalf = lane >> 5;      // k-octet = ic-octet
    const int tx0 = (blockIdx.x % 6) * 32;
    const int ty0 = (blockIdx.x / 6) * TSY;
    const int ob = blockIdx.y;
    const int bz = blockIdx.z;

    const ushort_t* bin = inp + (size_t)bz * in_bstr;

    // m-frag = one row of 32 px; wave wv owns rows wv*MF .. wv*MF+MF-1;
    // lane-half selects the ic-octet plane within the halo buffer
    int pixbase[MF];
    #pragma unroll
    for (int mf = 0; mf < MF; ++mf)
        pixbase[mf] = (lhalf * HGR_P + (wv * MF + mf) * 34 + ln31) * 8;

    f32x16 acc[MF][NF];
    #pragma unroll
    for (int mf = 0; mf < MF; ++mf)
        #pragma unroll
        for (int nf = 0; nf < NF; ++nf) {
            int o = ob * OTC + nf * 32 + ln31;
            float bv = (o < c_out) ? bias[o] : 0.f;
            #pragma unroll
            for (int r = 0; r < 16; ++r) acc[mf][nf][r] = bv;
        }

    const ushort_t* wbase = wt + (size_t)ob * NCHUNK * WGR * 8;

    auto stage_halo = [&](int buf, int cc) {
        const ushort_t* ih = bin + (size_t)(2 * cc) * PPG * 8;
        ushort_t* dx = s_x + buf * (HSLOT * 64 * 8);
        #pragma unroll
        for (int i = 0; i < HPW; ++i) {
            int j = wv * HPW + i;
            int hg = j * 64 + lane;
            int hgc = hg < HGR_T ? hg : HGR_T - 1;   // clamp: pad lanes rewrite last granule
            int pl = hgc / HGR_P;
            int rem = hgc - pl * HGR_P;
            int r = rem / 34, c = rem - r * 34;
            size_t sg = ((size_t)pl * PPG + (size_t)(ty0 + r) * PH + (tx0 + c)) * 8;
            gld_lds16(&ih[sg], &dx[j * 64 * 8]);
        }
    };
    auto stage_w = [&](int cc) {
        const ushort_t* wch = wbase + (size_t)cc * WGR * 8;
        for (int j = wv; j < WSLOT; j += 4) {    // per-wave count may differ: ok
            int wg = j * 64 + lane;
            int wgc = wg < WGR ? wg : WGR - 1;
            gld_lds16(&wch[(size_t)wgc * 8], &s_w[j * 64 * 8]);
        }
    };

    // prologue: halo 0,1 + weights 0 in flight; drain once (cheap, once per kernel)
    stage_halo(0, 0);
    stage_w(0);
    if (NCHUNK > 1) stage_halo(1, 1);
    vmcnt_wait<0>();
    __builtin_amdgcn_s_barrier();
    __builtin_amdgcn_sched_barrier(0);

    for (int cc = 0; cc < NCHUNK; ++cc) {
        const int cur = cc & 1;
        const ushort_t* xh = s_x + cur * (HSLOT * 64 * 8);
        #pragma unroll
        for (int t = 0; t < 9; ++t) {
            const int hof = ((t / 3) * 34 + (t % 3)) * 8;
            frag8 bh[NF];
            #pragma unroll
            for (int nf = 0; nf < NF; ++nf)
                bh[nf] = *(const frag8*)&s_w[((t * 2 + lhalf) * WOS + nf * 32 + ln31) * 8];
            #pragma unroll
            for (int mf = 0; mf < MF; ++mf) {
                frag8 ah = *(const frag8*)&xh[pixbase[mf] + hof];
                #pragma unroll
                for (int nf = 0; nf < NF; ++nf)
                    acc[mf][nf] = __builtin_amdgcn_mfma_f32_32x32x16_bf16(ah, bh[nf], acc[mf][nf], 0, 0, 0);
            }
        }
        if (cc + 1 == NCHUNK) break;
        __builtin_amdgcn_sched_barrier(0);
        __builtin_amdgcn_s_barrier();          // A: all waves done reading buffers
        if (cc + 2 < NCHUNK) {
            stage_w(cc + 1);                   // overwrite single weight buffer
            stage_halo(cur, cc + 2);           // overwrite just-consumed halo buffer
            vmcnt_wait<HPW>();                 // w(cc+1)+halo(cc+1) landed; halo(cc+2) flies
        } else {
            stage_w(cc + 1);
            vmcnt_wait<0>();                   // tail: drain
        }
        __builtin_amdgcn_s_barrier();          // B: chunk cc+1 ready
        __builtin_amdgcn_sched_barrier(0);
    }

    if constexpr (!LAST) {
        // ---- epilogue: reg j=4i+r: px col m = 8i + 4*lhalf + r; row = wv*MF+mf ----
        #pragma unroll
        for (int mf = 0; mf < MF; ++mf) {
            int gy = ty0 + wv * MF + mf;
            #pragma unroll
            for (int nf = 0; nf < NF; ++nf) {
                int o = ob * OTC + nf * 32 + ln31;
                if (o < c_out) {
                    #pragma unroll
                    for (int i = 0; i < 4; ++i) {
                        int px = tx0 + i * 8 + lhalf * 4;
                        ushort_t* bout = outp + (size_t)bz * out_bstr;
                        size_t g0 = ((size_t)(o >> 3) * PPG + (size_t)(gy + 1) * PH + (px + 1)) * 8 + (o & 7);
                        #pragma unroll
                        for (int r = 0; r < 4; ++r)
                            bout[g0 + (size_t)r * 8] = b16(acc[mf][nf][4 * i + r]);
                    }
                }
            }
        }
    } else {
        // ---- fused apply epilogue (conv3): all vm loads drained before break ----
        __builtin_amdgcn_s_barrier();          // staging LDS now free for ks tile
        // write bf16 ks tile: smem[o*256 + (p ^ ((o&7)<<2))], o in [0,96), p in [0,256)
        #pragma unroll
        for (int mf = 0; mf < MF; ++mf) {
            int lrow = wv * MF + mf;
            #pragma unroll
            for (int nf = 0; nf < NF; ++nf) {
                int o = nf * 32 + ln31;
                #pragma unroll
                for (int i = 0; i < 4; ++i) {
                    int pbase = lrow * 32 + i * 8 + lhalf * 4;
                    #pragma unroll
                    for (int r = 0; r < 4; ++r) {
                        int p = pbase + r;
                        smem[o * 256 + (p ^ ((o & 7) << 2))] = b16(acc[mf][nf][4 * i + r]);
                    }
                }
            }
        }
        __builtin_amdgcn_s_barrier();
        // per-thread 5x5x3 apply for its own pixel
        const int p = tid;
        const int gy = ty0 + (p >> 5);
        const int gx = tx0 + (p & 31);
        const float* xb = xin + (size_t)bz * 3 * PLANE;
        float* ob2 = outf + (size_t)bz * 3 * PLANE;
        float a[3] = {0.f, 0.f, 0.f};
        #pragma unroll
        for (int pt = 0; pt < 25; ++pt) {
            const int di = pt / 5, dj = pt % 5;
            int yy = gy + di - 2, xx = gx + dj - 2;
            bool inb = (yy >= 0 && yy < HW && xx >= 0 && xx < HW);
            #pragma unroll
            for (int c = 0; c < 3; ++c) {
                int k = pt * 3 + c;
                float kv = b16f(smem[k * 256 + (p ^ ((k & 7) << 2))]);
                float xv = inb ? xb[(size_t)c * PLANE + yy * HW + xx] : 0.f;
                a[c] = fmaf(kv, xv, a[c]);
            }
        }
        #pragma unroll
        for (int c = 0; c < 3; ++c)
            ob2[(size_t)c * PLANE + gy * HW + gx] = a[c];
    }
}

extern "C" void kernel_launch(void* const* d_in, const int* in_sizes, int n_in,
                              void* d_out, int out_size, void* d_ws, size_t ws_size,
                              hipStream_t stream) {
    const float* feature_x = (const float*)d_in[0];
    const float* x  = (const float*)d_in[1];
    const float* W1 = (const float*)d_in[2];
    const float* b1 = (const float*)d_in[3];
    const float* W2 = (const float*)d_in[4];
    const float* b2 = (const float*)d_in[5];
    const float* W3 = (const float*)d_in[6];
    const float* b3 = (const float*)d_in[7];
    float* out = (float*)d_out;

    const size_t PLN32 = (size_t)32 * PPG * 8;   // 9,634,816 ush (single bf16 plane/batch)
    const size_t PLN8  = (size_t)8 * PPG * 8;    // 2,408,704 ush
    // tap-major weights: [NOB][NCHUNK][9][2][OTC+4][8]
    const size_t W1SZ = (size_t)4 * 4  * 9 * 2 * 68  * 8;   // 156,672
    const size_t W2SZ = (size_t)4 * 16 * 9 * 2 * 68  * 8;   // 626,688
    const size_t W3SZ = (size_t)1 * 16 * 9 * 2 * 100 * 8;   // 230,400
    const size_t WTOT = W1SZ + W2SZ + W3SZ;
    // NB=4: y1[4] + y2[4] + weights <= 158,416,896 B proven (r16).
    const size_t FULL4 = (8 * PLN32 + WTOT) * 2;
    const int NB = (ws_size >= FULL4) ? 4 : 2;

    ushort_t* y1 = (ushort_t*)d_ws;              // [NB] planes, stride PLN32
    ushort_t* y2 = y1 + (size_t)NB * PLN32;
    ushort_t* wb = y2 + (size_t)NB * PLN32;
    ushort_t* w1 = wb;
    ushort_t* w2 = w1 + W1SZ;
    ushort_t* w3 = w2 + W2SZ;
    ushort_t* fx  = y2;                          // fx aliases y2 region, stride PLN8

    dim3 blk(256);
    wtrans_kernel<<<256, blk, 0, stream>>>(W1, w1, 64, 256, 4, 64, (int)W1SZ);
    wtrans_kernel<<<256, blk, 0, stream>>>(W2, w2, 256, 256, 16, 64, (int)W2SZ);
    wtrans_kernel<<<256, blk, 0, stream>>>(W3, w3, 256, 75, 16, 96, (int)W3SZ);

    // conv1/conv2: MF=4 tile 16x32 -> 72 spatial; conv3: MF=2/OTC=96 tile 8x32 -> 144 spatial
    dim3 g12(72, 4, NB), g3(144, 1, NB);
    for (int bp = 0; bp < 4 / NB; ++bp) {
        const float* fxsrc = feature_x + (size_t)bp * NB * 64 * PLANE;
        const float* x_b   = x   + (size_t)bp * NB * 3 * PLANE;
        float* out_b       = out + (size_t)bp * NB * 3 * PLANE;
        // Re-zero borders each call (workspace 0xAA-poisoned before timing; epilogues
        // only write plane interiors).
        zborder_kernel<<<97, blk, 0, stream>>>(y1, NB * 32);
        zborder_kernel<<<97, blk, 0, stream>>>(y2, NB * 32);
        packfx_kernel<<<1024, blk, 0, stream>>>(fxsrc, fx, NB, PLN8);
        conv_mfma< 4, 64, 4, false><<<g12, blk, 0, stream>>>(
            fx, w1, b1, 256, y1, nullptr, nullptr, PLN8, PLN32);
        conv_mfma<16, 64, 4, false><<<g12, blk, 0, stream>>>(
            y1, w2, b2, 256, y2, nullptr, nullptr, PLN32, PLN32);
        conv_mfma<16, 96, 2, true ><<<g3, blk, 0, stream>>>(
            y2, w3, b3, 75, nullptr, x_b, out_b, PLN32, 0);
    }
}

// Round 24
// 332.445 us; speedup vs baseline: 1.2909x; 1.1157x over previous
//
#include <hip/hip_runtime.h>
#include <hip/hip_bf16.h>
#include <stdint.h>

#define HW 192
#define PLANE (HW * HW)
#define PH 194
#define PPG (PH * PH)      // 37636 granules per padded 8-ch plane

typedef __attribute__((ext_vector_type(8))) short frag8;
typedef __attribute__((ext_vector_type(16))) float f32x16;
typedef unsigned short ushort_t;

__device__ __forceinline__ ushort_t b16(float v) {
    __hip_bfloat16 b = __float2bfloat16(v);
    return __builtin_bit_cast(ushort_t, b);
}
__device__ __forceinline__ float b16f(ushort_t u) {
    return __bfloat162float(__builtin_bit_cast(__hip_bfloat16, u));
}

// async 16B global->LDS copy: per-lane global src, wave-uniform LDS base (+lane*16)
__device__ __forceinline__ void gld_lds16(const ushort_t* g, ushort_t* s) {
    __builtin_amdgcn_global_load_lds(
        (const __attribute__((address_space(1))) uint32_t*)(const void*)g,
        (__attribute__((address_space(3))) uint32_t*)(void*)s, 16, 0, 0);
}

template<int N> __device__ __forceinline__ void vmcnt_wait() {
    static_assert(N == 0 || N == 3 || N == 4, "unsupported vmcnt");
    if constexpr (N == 0) asm volatile("s_waitcnt vmcnt(0)" ::: "memory");
    else if constexpr (N == 3) asm volatile("s_waitcnt vmcnt(3)" ::: "memory");
    else if constexpr (N == 4) asm volatile("s_waitcnt vmcnt(4)" ::: "memory");
}

// W[O][C_IN][3][3] f32 -> wt [NOB][NCHUNK][9][2][WOS][8] bf16.
// Tap-major, 16-ic chunks: chunk cc, ic-octet h, tap t. o-pad (WOS>OTC) breaks
// LDS bank aliasing between the two lane-half B-reads (r11 lesson).
// Pad granules and o>=C_OUT are zero.
__global__ __launch_bounds__(256) void wtrans_kernel(
    const float* __restrict__ w, ushort_t* __restrict__ wt,
    int C_IN, int C_OUT, int NCHUNK, int OTC, int WOS, int total)
{
    for (int idx = blockIdx.x * 256 + threadIdx.x; idx < total; idx += gridDim.x * 256) {
        int ic = idx & 7;
        int g = idx >> 3;
        int o = g % WOS; g /= WOS;
        int h = g & 1; g >>= 1;
        int t = g % 9; g /= 9;
        int cc = g % NCHUNK;
        int ob = g / NCHUNK;
        int og = ob * OTC + o;
        float v = 0.f;
        if (o < OTC && og < C_OUT)
            v = w[((size_t)og * C_IN + cc * 16 + h * 8 + ic) * 9 + t];
        wt[idx] = b16(v);
    }
}

// src [nb*64][H][W] f32 -> per-batch padded bf16 planes [8][PH][PH][8] at b*bstr
__global__ __launch_bounds__(256) void packfx_kernel(
    const float* __restrict__ src, ushort_t* __restrict__ d,
    int nb, size_t bstr)
{
    int n = nb * 64 * PLANE;
    for (int idx = blockIdx.x * 256 + threadIdx.x; idx < n; idx += gridDim.x * 256) {
        int c = idx / PLANE;
        int p = idx - c * PLANE;
        int b = c >> 6, cc = c & 63;
        int y = p / HW, x = p - y * HW;
        size_t di = (size_t)b * bstr + ((size_t)(cc >> 3) * PPG + (size_t)(y + 1) * PH + (x + 1)) * 8 + (cc & 7);
        d[di] = b16(src[idx]);
    }
}

// zero the 1-px borders of nchunks padded planes
__global__ __launch_bounds__(256) void zborder_kernel(
    ushort_t* __restrict__ ph, int nchunks)
{
    int total = nchunks * 772;
    for (int i = blockIdx.x * 256 + threadIdx.x; i < total; i += gridDim.x * 256) {
        int chunk = i / 772, b = i - chunk * 772;
        int y, x;
        if (b < 194)      { y = 0;   x = b; }
        else if (b < 388) { y = 193; x = b - 194; }
        else { int r = b - 388; y = 1 + (r >> 1); x = (r & 1) ? 193 : 0; }
        size_t g = ((size_t)chunk * PPG + (size_t)y * PH + x) * 8;
        *(uint4*)&ph[g] = make_uint4(0, 0, 0, 0);
    }
}

// 3x3 SAME conv, single-pass bf16 MFMA (32x32x16), tap-major K-loop
// (K-step = 16 consecutive ic; lane-half = ic-octet; 9 real taps looped -> zero
// tap-padding). Halo double-buffered with counted vmcnt; weights single-buffered
// (staged at barrier A; vmcnt ledger: issue w(cc+1) then halo(cc+2), wait
// vmcnt(HPW) -> newest HPW = halo(cc+2) stay in flight, w(cc+1)+halo(cc+1) landed).
// inp: [2*NCHUNK 8-ic planes][PH][PH][8] per batch; wt: [NOB][NCHUNK][9][2][WOS][8].
// Block: 256 thr (4 waves), (4*MF... actually TSY=4*MF? no: TSY rows) x 32 tile:
//   conv1/conv2: MF=3 -> 12x32 tile, LDS 53248B -> 3 blocks/CU (occupancy play);
//   conv3:       MF=2 -> 8x32 tile, OTC=96/WOS=98, LDS 53248B -> 3 blocks/CU.
// Wave wv owns MF one-row m-frags (conflict-free A-reads, r13/r14-verified).
// LAST=true (conv3): fused 5x5x3 apply epilogue via LDS ks tile (r22-verified).
// A row / B col = lane&31; C/D: col=lane&31, m=(reg&3)+8(reg>>2)+4(lane>>5).
// NOTE: no min-waves hint (rounds 5/8: hint below acc footprint -> scratch spill).
template<int NCHUNK, int OTC, int WOS, int MF, bool LAST>
__global__ __launch_bounds__(256) void conv_mfma(
    const ushort_t* __restrict__ inp, const ushort_t* __restrict__ wt,
    const float* __restrict__ bias, int c_out,
    ushort_t* __restrict__ outp, const float* __restrict__ xin,
    float* __restrict__ outf, size_t in_bstr, size_t out_bstr)
{
    constexpr int NF = OTC / 32;
    constexpr int TSY = 4 * MF;               // 12 or 8 rows
    constexpr int HGR_P = (TSY + 2) * 34;     // halo granules per 8-ic plane (476/340)
    constexpr int HGR_T = 2 * HGR_P;          // per 16-ic chunk (952/680)
    constexpr int HSLOT = (MF == 3) ? 16 : 12;    // 64-granule slots (mult of 4)
    constexpr int HPW = HSLOT / 4;            // uniform halo loads per wave (4/3)
    constexpr int WGR = 9 * 2 * WOS;          // weight granules per chunk (1224/1764)
    constexpr int WSLOT = (WGR + 63) / 64;    // 20 / 28
    constexpr int SMEM_USH = (2 * HSLOT + WSLOT) * 64 * 8;   // 26624 ush both
    static_assert(!LAST || SMEM_USH >= 96 * 256, "ks tile must fit LDS");
    __shared__ ushort_t smem[SMEM_USH];
    ushort_t* s_x = smem;                     // 2 halo buffers
    ushort_t* s_w = smem + 2 * HSLOT * 64 * 8;

    const int tid = threadIdx.x;
    const int wv = tid >> 6;          // 0..3
    const int lane = tid & 63;
    const int ln31 = lane & 31;       // A row (pixel col) / B col (o) / D col
    const int lhalf = lane >> 5;      // k-octet = ic-octet
    const int tx0 = (blockIdx.x % 6) * 32;
    const int ty0 = (blockIdx.x / 6) * TSY;
    const int ob = blockIdx.y;
    const int bz = blockIdx.z;

    const ushort_t* bin = inp + (size_t)bz * in_bstr;

    // m-frag = one row of 32 px; wave wv owns rows wv*MF .. wv*MF+MF-1;
    // lane-half selects the ic-octet plane within the halo buffer
    int pixbase[MF];
    #pragma unroll
    for (int mf = 0; mf < MF; ++mf)
        pixbase[mf] = (lhalf * HGR_P + (wv * MF + mf) * 34 + ln31) * 8;

    f32x16 acc[MF][NF];
    #pragma unroll
    for (int mf = 0; mf < MF; ++mf)
        #pragma unroll
        for (int nf = 0; nf < NF; ++nf) {
            int o = ob * OTC + nf * 32 + ln31;
            float bv = (o < c_out) ? bias[o] : 0.f;
            #pragma unroll
            for (int r = 0; r < 16; ++r) acc[mf][nf][r] = bv;
        }

    const ushort_t* wbase = wt + (size_t)ob * NCHUNK * WGR * 8;

    auto stage_halo = [&](int buf, int cc) {
        const ushort_t* ih = bin + (size_t)(2 * cc) * PPG * 8;
        ushort_t* dx = s_x + buf * (HSLOT * 64 * 8);
        #pragma unroll
        for (int i = 0; i < HPW; ++i) {
            int j = wv * HPW + i;
            int hg = j * 64 + lane;
            int hgc = hg < HGR_T ? hg : HGR_T - 1;   // clamp: pad lanes rewrite last granule
            int pl = hgc / HGR_P;
            int rem = hgc - pl * HGR_P;
            int r = rem / 34, c = rem - r * 34;
            size_t sg = ((size_t)pl * PPG + (size_t)(ty0 + r) * PH + (tx0 + c)) * 8;
            gld_lds16(&ih[sg], &dx[j * 64 * 8]);
        }
    };
    auto stage_w = [&](int cc) {
        const ushort_t* wch = wbase + (size_t)cc * WGR * 8;
        for (int j = wv; j < WSLOT; j += 4) {    // per-wave count may differ: ok
            int wg = j * 64 + lane;
            int wgc = wg < WGR ? wg : WGR - 1;
            gld_lds16(&wch[(size_t)wgc * 8], &s_w[j * 64 * 8]);
        }
    };

    // prologue: halo 0,1 + weights 0 in flight; drain once (cheap, once per kernel)
    stage_halo(0, 0);
    stage_w(0);
    if (NCHUNK > 1) stage_halo(1, 1);
    vmcnt_wait<0>();
    __builtin_amdgcn_s_barrier();
    __builtin_amdgcn_sched_barrier(0);

    for (int cc = 0; cc < NCHUNK; ++cc) {
        const int cur = cc & 1;
        const ushort_t* xh = s_x + cur * (HSLOT * 64 * 8);
        #pragma unroll
        for (int t = 0; t < 9; ++t) {
            const int hof = ((t / 3) * 34 + (t % 3)) * 8;
            frag8 bh[NF];
            #pragma unroll
            for (int nf = 0; nf < NF; ++nf)
                bh[nf] = *(const frag8*)&s_w[((t * 2 + lhalf) * WOS + nf * 32 + ln31) * 8];
            #pragma unroll
            for (int mf = 0; mf < MF; ++mf) {
                frag8 ah = *(const frag8*)&xh[pixbase[mf] + hof];
                #pragma unroll
                for (int nf = 0; nf < NF; ++nf)
                    acc[mf][nf] = __builtin_amdgcn_mfma_f32_32x32x16_bf16(ah, bh[nf], acc[mf][nf], 0, 0, 0);
            }
        }
        if (cc + 1 == NCHUNK) break;
        __builtin_amdgcn_sched_barrier(0);
        __builtin_amdgcn_s_barrier();          // A: all waves done reading buffers
        if (cc + 2 < NCHUNK) {
            stage_w(cc + 1);                   // overwrite single weight buffer
            stage_halo(cur, cc + 2);           // overwrite just-consumed halo buffer
            vmcnt_wait<HPW>();                 // w(cc+1)+halo(cc+1) landed; halo(cc+2) flies
        } else {
            stage_w(cc + 1);
            vmcnt_wait<0>();                   // tail: drain
        }
        __builtin_amdgcn_s_barrier();          // B: chunk cc+1 ready
        __builtin_amdgcn_sched_barrier(0);
    }

    if constexpr (!LAST) {
        // ---- epilogue: reg j=4i+r: px col m = 8i + 4*lhalf + r; row = wv*MF+mf ----
        #pragma unroll
        for (int mf = 0; mf < MF; ++mf) {
            int gy = ty0 + wv * MF + mf;
            #pragma unroll
            for (int nf = 0; nf < NF; ++nf) {
                int o = ob * OTC + nf * 32 + ln31;
                if (o < c_out) {
                    #pragma unroll
                    for (int i = 0; i < 4; ++i) {
                        int px = tx0 + i * 8 + lhalf * 4;
                        ushort_t* bout = outp + (size_t)bz * out_bstr;
                        size_t g0 = ((size_t)(o >> 3) * PPG + (size_t)(gy + 1) * PH + (px + 1)) * 8 + (o & 7);
                        #pragma unroll
                        for (int r = 0; r < 4; ++r)
                            bout[g0 + (size_t)r * 8] = b16(acc[mf][nf][4 * i + r]);
                    }
                }
            }
        }
    } else {
        // ---- fused apply epilogue (conv3): all vm loads drained before break ----
        __builtin_amdgcn_s_barrier();          // staging LDS now free for ks tile
        // write bf16 ks tile: smem[o*256 + (p ^ ((o&7)<<2))], o in [0,96), p in [0,256)
        #pragma unroll
        for (int mf = 0; mf < MF; ++mf) {
            int lrow = wv * MF + mf;
            #pragma unroll
            for (int nf = 0; nf < NF; ++nf) {
                int o = nf * 32 + ln31;
                #pragma unroll
                for (int i = 0; i < 4; ++i) {
                    int pbase = lrow * 32 + i * 8 + lhalf * 4;
                    #pragma unroll
                    for (int r = 0; r < 4; ++r) {
                        int p = pbase + r;
                        smem[o * 256 + (p ^ ((o & 7) << 2))] = b16(acc[mf][nf][4 * i + r]);
                    }
                }
            }
        }
        __builtin_amdgcn_s_barrier();
        // per-thread 5x5x3 apply for its own pixel
        const int p = tid;
        const int gy = ty0 + (p >> 5);
        const int gx = tx0 + (p & 31);
        const float* xb = xin + (size_t)bz * 3 * PLANE;
        float* ob2 = outf + (size_t)bz * 3 * PLANE;
        float a[3] = {0.f, 0.f, 0.f};
        #pragma unroll
        for (int pt = 0; pt < 25; ++pt) {
            const int di = pt / 5, dj = pt % 5;
            int yy = gy + di - 2, xx = gx + dj - 2;
            bool inb = (yy >= 0 && yy < HW && xx >= 0 && xx < HW);
            #pragma unroll
            for (int c = 0; c < 3; ++c) {
                int k = pt * 3 + c;
                float kv = b16f(smem[k * 256 + (p ^ ((k & 7) << 2))]);
                float xv = inb ? xb[(size_t)c * PLANE + yy * HW + xx] : 0.f;
                a[c] = fmaf(kv, xv, a[c]);
            }
        }
        #pragma unroll
        for (int c = 0; c < 3; ++c)
            ob2[(size_t)c * PLANE + gy * HW + gx] = a[c];
    }
}

extern "C" void kernel_launch(void* const* d_in, const int* in_sizes, int n_in,
                              void* d_out, int out_size, void* d_ws, size_t ws_size,
                              hipStream_t stream) {
    const float* feature_x = (const float*)d_in[0];
    const float* x  = (const float*)d_in[1];
    const float* W1 = (const float*)d_in[2];
    const float* b1 = (const float*)d_in[3];
    const float* W2 = (const float*)d_in[4];
    const float* b2 = (const float*)d_in[5];
    const float* W3 = (const float*)d_in[6];
    const float* b3 = (const float*)d_in[7];
    float* out = (float*)d_out;

    const size_t PLN32 = (size_t)32 * PPG * 8;   // 9,634,816 ush (single bf16 plane/batch)
    const size_t PLN8  = (size_t)8 * PPG * 8;    // 2,408,704 ush
    // tap-major weights: [NOB][NCHUNK][9][2][WOS][8]
    const size_t W1SZ = (size_t)4 * 4  * 9 * 2 * 68 * 8;    // 156,672
    const size_t W2SZ = (size_t)4 * 16 * 9 * 2 * 68 * 8;    // 626,688
    const size_t W3SZ = (size_t)1 * 16 * 9 * 2 * 98 * 8;    // 225,792
    const size_t WTOT = W1SZ + W2SZ + W3SZ;
    // NB=4: y1[4] + y2[4] + weights <= 158,416,896 B proven (r16).
    const size_t FULL4 = (8 * PLN32 + WTOT) * 2;
    const int NB = (ws_size >= FULL4) ? 4 : 2;

    ushort_t* y1 = (ushort_t*)d_ws;              // [NB] planes, stride PLN32
    ushort_t* y2 = y1 + (size_t)NB * PLN32;
    ushort_t* wb = y2 + (size_t)NB * PLN32;
    ushort_t* w1 = wb;
    ushort_t* w2 = w1 + W1SZ;
    ushort_t* w3 = w2 + W2SZ;
    ushort_t* fx  = y2;                          // fx aliases y2 region, stride PLN8

    dim3 blk(256);
    wtrans_kernel<<<256, blk, 0, stream>>>(W1, w1, 64, 256, 4, 64, 68, (int)W1SZ);
    wtrans_kernel<<<256, blk, 0, stream>>>(W2, w2, 256, 256, 16, 64, 68, (int)W2SZ);
    wtrans_kernel<<<256, blk, 0, stream>>>(W3, w3, 256, 75, 16, 96, 98, (int)W3SZ);

    // conv1/conv2: MF=3 tile 12x32 -> 96 spatial; conv3: MF=2/OTC=96 tile 8x32 -> 144 spatial
    dim3 g12(96, 4, NB), g3(144, 1, NB);
    for (int bp = 0; bp < 4 / NB; ++bp) {
        const float* fxsrc = feature_x + (size_t)bp * NB * 64 * PLANE;
        const float* x_b   = x   + (size_t)bp * NB * 3 * PLANE;
        float* out_b       = out + (size_t)bp * NB * 3 * PLANE;
        // Re-zero borders each call (workspace 0xAA-poisoned before timing; epilogues
        // only write plane interiors).
        zborder_kernel<<<97, blk, 0, stream>>>(y1, NB * 32);
        zborder_kernel<<<97, blk, 0, stream>>>(y2, NB * 32);
        packfx_kernel<<<1024, blk, 0, stream>>>(fxsrc, fx, NB, PLN8);
        conv_mfma< 4, 64, 68, 3, false><<<g12, blk, 0, stream>>>(
            fx, w1, b1, 256, y1, nullptr, nullptr, PLN8, PLN32);
        conv_mfma<16, 64, 68, 3, false><<<g12, blk, 0, stream>>>(
            y1, w2, b2, 256, y2, nullptr, nullptr, PLN32, PLN32);
        conv_mfma<16, 96, 98, 2, true ><<<g3, blk, 0, stream>>>(
            y2, w3, b3, 75, nullptr, x_b, out_b, PLN32, 0);
    }
}